// Round 6
// baseline (516.290 us; speedup 1.0000x reference)
//
#include <hip/hip_runtime.h>
#include <hip/hip_bf16.h>

#define D 128  // EMBED == LAYER == 128
#define BSHIFT 6          // 64 users per bucket
#define BUSERS (1 << BSHIFT)

// round-to-nearest f32 -> bf16 bits (values are normal floats here)
__device__ __forceinline__ unsigned int bf16rn(float f) {
  unsigned int u = __float_as_uint(f);
  return (u + 0x7fffu + ((u >> 16) & 1u)) >> 16;
}

// ---------------------------------------------------------------------------
// Kernel 1: P = item_emb @ W  — register-tiled SGEMM, bf16 output.
// Block = 256 threads (16x16), M-tile = 128 rows. Each thread: 8x8 micro-tile.
// ---------------------------------------------------------------------------
__global__ __launch_bounds__(256) void pw_kernel(
    const float* __restrict__ emb, const float* __restrict__ W,
    unsigned short* __restrict__ Pb, int n_items) {
  __shared__ float Al[128][132];   // +4 pad: 16B-aligned rows, bank spread
  __shared__ float Wl[128][128];
  const int tid = threadIdx.x;
  const int m0 = blockIdx.x * 128;

  {
    const float4* W4 = reinterpret_cast<const float4*>(W);
    float4* Wl4 = reinterpret_cast<float4*>(&Wl[0][0]);
#pragma unroll
    for (int i = 0; i < 16; ++i) Wl4[tid + 256 * i] = W4[tid + 256 * i];
  }
  {
    const float4* E4 = reinterpret_cast<const float4*>(emb);
#pragma unroll
    for (int i = 0; i < 16; ++i) {
      const int f = tid + 256 * i;
      const int row = f >> 5;
      const int c4 = (f & 31) * 4;
      const int r = m0 + row;
      float4 v = {0.f, 0.f, 0.f, 0.f};
      if (r < n_items) v = E4[(size_t)r * 32 + (f & 31)];
      *reinterpret_cast<float4*>(&Al[row][c4]) = v;
    }
  }
  __syncthreads();

  const int tx = tid & 15;
  const int ty = tid >> 4;
  const int c0 = tx * 8;
  const int r0 = ty * 8;

  float acc[8][8];
#pragma unroll
  for (int i = 0; i < 8; ++i)
#pragma unroll
    for (int j = 0; j < 8; ++j) acc[i][j] = 0.f;

  for (int k = 0; k < D; ++k) {
    float a[8];
#pragma unroll
    for (int i = 0; i < 8; ++i) a[i] = Al[r0 + i][k];
    const float4 w0 = *reinterpret_cast<const float4*>(&Wl[k][c0]);
    const float4 w1 = *reinterpret_cast<const float4*>(&Wl[k][c0 + 4]);
#pragma unroll
    for (int i = 0; i < 8; ++i) {
      acc[i][0] += a[i] * w0.x; acc[i][1] += a[i] * w0.y;
      acc[i][2] += a[i] * w0.z; acc[i][3] += a[i] * w0.w;
      acc[i][4] += a[i] * w1.x; acc[i][5] += a[i] * w1.y;
      acc[i][6] += a[i] * w1.z; acc[i][7] += a[i] * w1.w;
    }
  }

#pragma unroll
  for (int i = 0; i < 8; ++i) {
    const int r = m0 + r0 + i;
    if (r < n_items) {
      uint4 o;
      o.x = bf16rn(acc[i][0]) | (bf16rn(acc[i][1]) << 16);
      o.y = bf16rn(acc[i][2]) | (bf16rn(acc[i][3]) << 16);
      o.z = bf16rn(acc[i][4]) | (bf16rn(acc[i][5]) << 16);
      o.w = bf16rn(acc[i][6]) | (bf16rn(acc[i][7]) << 16);
      // row = 128 bf16 = 64 uints; this thread covers uints tx*4..tx*4+3
      *reinterpret_cast<uint4*>(reinterpret_cast<unsigned int*>(Pb) +
                                (size_t)r * 64 + tx * 4) = o;
    }
  }
}

// ---------------------------------------------------------------------------
// Kernel 2: histogram of destination rows.
// ---------------------------------------------------------------------------
__global__ __launch_bounds__(256) void hist_kernel(
    const int* __restrict__ rows, int* __restrict__ counts, int n_edges) {
  const int e = blockIdx.x * blockDim.x + threadIdx.x;
  if (e < n_edges) atomicAdd(&counts[rows[e]], 1);
}

// ---------------------------------------------------------------------------
// Scan (multi-block).
// ---------------------------------------------------------------------------
__global__ __launch_bounds__(1024) void blocksum_kernel(
    const int* __restrict__ counts, int* __restrict__ partials, int n) {
  __shared__ int lds[1024];
  const int tid = threadIdx.x;
  const int i = blockIdx.x * 1024 + tid;
  lds[tid] = (i < n) ? counts[i] : 0;
  __syncthreads();
  for (int s = 512; s > 0; s >>= 1) {
    if (tid < s) lds[tid] += lds[tid + s];
    __syncthreads();
  }
  if (tid == 0) partials[blockIdx.x] = lds[0];
}

__global__ __launch_bounds__(1024) void scanpart_kernel(
    const int* __restrict__ partials, int* __restrict__ blockoff, int nb,
    int* __restrict__ row_start, int n_users, int n_edges) {
  __shared__ int lds[1024];
  const int tid = threadIdx.x;
  const int x = (tid < nb) ? partials[tid] : 0;
  lds[tid] = x;
  __syncthreads();
  for (int s = 1; s < 1024; s <<= 1) {
    const int y = (tid >= s) ? lds[tid - s] : 0;
    __syncthreads();
    lds[tid] += y;
    __syncthreads();
  }
  if (tid < nb) blockoff[tid] = lds[tid] - x;
  if (tid == 0) row_start[n_users] = n_edges;
}

__global__ __launch_bounds__(1024) void localscan_kernel(
    const int* __restrict__ counts, const int* __restrict__ blockoff,
    int* __restrict__ row_start, int* __restrict__ cursor, int n) {
  __shared__ int lds[1024];
  const int tid = threadIdx.x;
  const int i = blockIdx.x * 1024 + tid;
  const int x = (i < n) ? counts[i] : 0;
  lds[tid] = x;
  __syncthreads();
  for (int s = 1; s < 1024; s <<= 1) {
    const int y = (tid >= s) ? lds[tid - s] : 0;
    __syncthreads();
    lds[tid] += y;
    __syncthreads();
  }
  if (i < n) {
    const int excl = blockoff[blockIdx.x] + lds[tid] - x;
    row_start[i] = excl;
    cursor[i] = excl;
  }
}

// ---------------------------------------------------------------------------
// Kernel 3b: init bucket cursors from row_start.
// ---------------------------------------------------------------------------
__global__ __launch_bounds__(256) void binit_kernel(
    const int* __restrict__ row_start, int* __restrict__ bcursor, int nbuck,
    int n_users) {
  const int b = blockIdx.x * blockDim.x + threadIdx.x;
  if (b < nbuck) {
    int u = b << BSHIFT;
    bcursor[b] = row_start[u < n_users ? u : n_users];
  }
}

// ---------------------------------------------------------------------------
// Kernel 4a (pass A): append edges to their bucket's staging segment.
// Pack: (row & 63) << 16 | col   (requires n_items <= 65536). val separate.
// Only ~nbuck active cursors -> scatter working set is L2-resident.
// ---------------------------------------------------------------------------
__global__ __launch_bounds__(256) void binfill_kernel(
    const int* __restrict__ rows, const int* __restrict__ cols,
    const float* __restrict__ vals, int* __restrict__ bcursor,
    unsigned int* __restrict__ spack, float* __restrict__ sval, int n_edges) {
  const int e = blockIdx.x * blockDim.x + threadIdx.x;
  if (e >= n_edges) return;
  const int r = rows[e];
  const int b = r >> BSHIFT;
  const int pos = atomicAdd(&bcursor[b], 1);
  spack[pos] = ((unsigned int)(r & (BUSERS - 1)) << 16) | (unsigned int)cols[e];
  sval[pos] = vals[e];
}

// ---------------------------------------------------------------------------
// Kernel 4b (pass B): one block per bucket; scatter staged edges to final
// per-user CSR slots. All writes land in the bucket's contiguous region.
// ---------------------------------------------------------------------------
__global__ __launch_bounds__(256) void csr_kernel(
    const unsigned int* __restrict__ spack, const float* __restrict__ sval,
    const int* __restrict__ row_start, int* __restrict__ cursor,
    int2* __restrict__ colval, int n_users) {
  const int b = blockIdx.x;
  const int u0 = b << BSHIFT;
  const int u1 = (u0 + BUSERS < n_users) ? (u0 + BUSERS) : n_users;
  const int beg = row_start[u0];
  const int end = row_start[u1];
  for (int i = beg + threadIdx.x; i < end; i += blockDim.x) {
    const unsigned int p = spack[i];
    const int r = u0 + (int)(p >> 16);
    const int c = (int)(p & 0xffffu);
    const int pos = atomicAdd(&cursor[r], 1);
    colval[pos] = make_int2(c, __float_as_int(sval[i]));
  }
}

// ---------------------------------------------------------------------------
// Kernel 5: per-user gather. 32 lanes per user; bf16 P rows (256B each).
// out[u] = nj[u] * sum_j val[j] * P[col[j]]
// ---------------------------------------------------------------------------
__global__ __launch_bounds__(256) void gather_kernel(
    const unsigned int* __restrict__ Pb,  // bf16 pairs, 64 uints per row
    const int* __restrict__ row_start, const int2* __restrict__ colval,
    const float* __restrict__ nj, float* __restrict__ out, int n_users) {
  const long long tid = (long long)blockIdx.x * blockDim.x + threadIdx.x;
  const int u = (int)(tid >> 5);
  if (u >= n_users) return;
  const int lane = (int)(tid & 31);

  const int jbeg = row_start[u];
  const int jend = row_start[u + 1];
  float4 acc = {0.f, 0.f, 0.f, 0.f};
  for (int j = jbeg; j < jend; ++j) {
    const int2 cv = colval[j];
    const float v = __int_as_float(cv.y);
    const uint2 pv =
        *reinterpret_cast<const uint2*>(Pb + (size_t)cv.x * 64 + lane * 2);
    acc.x += v * __uint_as_float(pv.x << 16);
    acc.y += v * __uint_as_float(pv.x & 0xffff0000u);
    acc.z += v * __uint_as_float(pv.y << 16);
    acc.w += v * __uint_as_float(pv.y & 0xffff0000u);
  }
  const float s = nj[u];
  acc.x *= s; acc.y *= s; acc.z *= s; acc.w *= s;
  *reinterpret_cast<float4*>(out + (size_t)u * D + lane * 4) = acc;
}

extern "C" void kernel_launch(void* const* d_in, const int* in_sizes, int n_in,
                              void* d_out, int out_size, void* d_ws,
                              size_t ws_size, hipStream_t stream) {
  const float* item_emb = (const float*)d_in[0];  // [n_items, 128]
  const float* user_nj  = (const float*)d_in[1];  // [n_users, 1]
  const float* weight   = (const float*)d_in[2];  // [128, 128]
  const float* adj_vals = (const float*)d_in[3];  // [E]
  const int*   adj_rows = (const int*)d_in[4];    // [E]
  const int*   adj_cols = (const int*)d_in[5];    // [E]

  const int n_items = in_sizes[0] / D;
  const int n_users = in_sizes[1];
  const int n_edges = in_sizes[3];
  float* out = (float*)d_out;

  const int nb = (n_users + 1023) / 1024;            // scan blocks
  const int nbuck = (n_users + BUSERS - 1) >> BSHIFT; // buckets

  // ---- workspace layout (256B-aligned) ----
  auto align256 = [](size_t x) { return (x + 255) & ~(size_t)255; };
  char* ws = (char*)d_ws;
  size_t off = 0;
  unsigned short* Pb = (unsigned short*)(ws + off);
  off = align256(off + (size_t)n_items * D * 2);           // 12.8 MB bf16
  int* counts = (int*)(ws + off);      off = align256(off + (size_t)n_users * 4);
  int* row_start = (int*)(ws + off);   off = align256(off + (size_t)(n_users + 1) * 4);
  int* cursor = (int*)(ws + off);      off = align256(off + (size_t)n_users * 4);
  unsigned int* spack = (unsigned int*)(ws + off);
  off = align256(off + (size_t)n_edges * 4);
  float* sval = (float*)(ws + off);    off = align256(off + (size_t)n_edges * 4);
  int2* colval = (int2*)(ws + off);    off = align256(off + (size_t)n_edges * 8);
  int* partials = (int*)(ws + off);    off = align256(off + (size_t)nb * 4);
  int* blockoff = (int*)(ws + off);    off = align256(off + (size_t)nb * 4);
  int* bcursor = (int*)(ws + off);     off = align256(off + (size_t)nbuck * 4);

  // 1) P = item_emb @ W  (bf16 output)
  pw_kernel<<<(n_items + 127) / 128, 256, 0, stream>>>(item_emb, weight, Pb,
                                                       n_items);

  // 2) histogram of rows
  hipMemsetAsync(counts, 0, (size_t)n_users * 4, stream);
  hist_kernel<<<(n_edges + 255) / 256, 256, 0, stream>>>(adj_rows, counts,
                                                         n_edges);

  // 3) multi-block exclusive scan -> row_start, cursor
  blocksum_kernel<<<nb, 1024, 0, stream>>>(counts, partials, n_users);
  scanpart_kernel<<<1, 1024, 0, stream>>>(partials, blockoff, nb, row_start,
                                          n_users, n_edges);
  localscan_kernel<<<nb, 1024, 0, stream>>>(counts, blockoff, row_start,
                                            cursor, n_users);

  // 4) two-level bin: bucket append, then per-bucket CSR scatter (L2-local)
  binit_kernel<<<(nbuck + 255) / 256, 256, 0, stream>>>(row_start, bcursor,
                                                        nbuck, n_users);
  binfill_kernel<<<(n_edges + 255) / 256, 256, 0, stream>>>(
      adj_rows, adj_cols, adj_vals, bcursor, spack, sval, n_edges);
  csr_kernel<<<nbuck, 256, 0, stream>>>(spack, sval, row_start, cursor, colval,
                                        n_users);

  // 5) per-user gather (writes every output row -> no memset needed)
  {
    const long long total_threads = (long long)n_users * 32;
    const int blocks = (int)((total_threads + 255) / 256);
    gather_kernel<<<blocks, 256, 0, stream>>>(
        reinterpret_cast<const unsigned int*>(Pb), row_start, colval, user_nj,
        out, n_users);
  }
}